// Round 1
// baseline (63.171 us; speedup 1.0000x reference)
//
#include <hip/hip_runtime.h>

// out[b,c,m] = sum_{j=0}^{127} x[b, (128m - j) mod 16000] * (kr[c,j] + i*ki[c,j])
//   x: (32, 1, 16000) fp32; kernels: (40, 128) fp32 each
//   out: (32, 40, 125) complex64 -> planar [all re | all im] (confirmed round 2)
//
// Round 5: stride==taps==128 -> tap windows per m are DISJOINT. The whole op is
//   a GEMM:  A(4000x128) . B(128x80),  A[r=b*125+m][j] = x[b,(128m-j) mod L],
//   B = [kr | ki]^T (bf16).  Two launches:
//     1) prep: materialize A as bf16 hi/lo split (keeps ~16 mantissa bits of x,
//        numerics unchanged vs round-4 which already rounded kernels to bf16)
//        + kernels->bf16, all into d_ws.
//     2) gemm: 1250 independent 16x16 output tiles, one per wave. No LDS, no
//        barriers: 12 coalesced dwordx4 fragment loads + 8 mfma_f32_16x16x32_bf16
//        + scatter epilogue. ~70 instr/wave vs ~770 instr/thread in the scalar
//        version (which was ~100x off both rooflines).
#define BB     32
#define CC     40
#define LL     16000
#define KK     128
#define MM     125
#define KPAD   129                  // legacy kernel LDS stride
#define NOUT   (BB * CC * MM)       // 160000 complex outputs
#define RTOT   (BB * MM)            // 4000 GEMM rows
#define NCOL   (2 * CC)             // 80 GEMM cols (re | im)
#define NTILE  ((RTOT / 16) * (NCOL / 16))   // 250 * 5 = 1250 tiles

using short8 = __attribute__((ext_vector_type(8))) short;  // 8 bf16 (MFMA A/B frag)
using f32x4  = __attribute__((ext_vector_type(4))) float;  // MFMA C/D frag

__device__ __forceinline__ unsigned int bf16_rne(float v) {
    unsigned int u = __float_as_uint(v);
    return (u + 0x7FFFu + ((u >> 16) & 1u)) >> 16;
}

// ---------------------------------------------------------------------------
// Prep: ws layout (dwords):
//   whi[256000]  : A_hi bf16 pairs, ushort index r*128 + k   (1,024,000 B)
//   wlo[256000]  : A_lo bf16 pairs, same indexing            (1,024,000 B)
//   wkb[5120]    : B    bf16 pairs, ushort index col*128 + k (   20,480 B)
// Blocks 0..999: x -> A hi/lo (256000 dword pairs). Blocks 1000..1019: kernels.
// ---------------------------------------------------------------------------
__global__ __launch_bounds__(256) void ISAC_prep(
    const float* __restrict__ x,
    const float* __restrict__ kr,
    const float* __restrict__ ki,
    unsigned int* __restrict__ whi,
    unsigned int* __restrict__ wlo,
    unsigned int* __restrict__ wkb)
{
    int bid = blockIdx.x;
    if (bid < 1000) {
        int pid = bid * 256 + threadIdx.x;     // 0..255999 == r*64 + kp
        int r  = pid >> 6;
        int kp = pid & 63;
        int b  = r / MM;
        int m  = r - b * MM;
        int i0 = m * KK - 2 * kp;  if (i0 < 0) i0 += LL;   // tap k=2kp
        int i1 = i0 - 1;           if (i1 < 0) i1 += LL;   // tap k=2kp+1
        float xa = x[b * LL + i0];
        float xb = x[b * LL + i1];
        unsigned int ha = bf16_rne(xa), hb = bf16_rne(xb);
        float la = xa - __uint_as_float(ha << 16);
        float lb = xb - __uint_as_float(hb << 16);
        whi[pid] = ha | (hb << 16);
        wlo[pid] = bf16_rne(la) | (bf16_rne(lb) << 16);
    } else {
        int pid = (bid - 1000) * 256 + threadIdx.x;        // 0..5119 == col*64 + kp
        if (pid < NCOL * 64) {
            int col = pid >> 6;
            int kp  = pid & 63;
            const float* src = (col < CC) ? (kr + col * KK) : (ki + (col - CC) * KK);
            wkb[pid] = bf16_rne(src[2 * kp]) | (bf16_rne(src[2 * kp + 1]) << 16);
        }
    }
}

// ---------------------------------------------------------------------------
// GEMM: one 16x16 tile per wave. Fragment layouts (mfma_f32_16x16x32_bf16):
//   A: row = lane&15, k = (lane>>4)*8 + e   -> 16B load at [row*128 + ks*32 + g*8]
//   B: col = lane&15, k = (lane>>4)*8 + e   -> same addressing into wkb
//   D: col = lane&15, row = (lane>>4)*4 + e (guide m89-verified)
// ---------------------------------------------------------------------------
__global__ __launch_bounds__(256) void ISAC_gemm(
    const unsigned short* __restrict__ whi,
    const unsigned short* __restrict__ wlo,
    const unsigned short* __restrict__ wkb,
    float* __restrict__ out)
{
    int tile = blockIdx.x * 4 + (threadIdx.x >> 6);
    if (tile >= NTILE) return;
    int lane = threadIdx.x & 63;
    int rt = tile / 5;
    int ct = tile - rt * 5;
    int row = lane & 15;
    int g   = lane >> 4;

    const short8* pa = (const short8*)(whi + ((rt * 16 + row) * KK + g * 8));
    const short8* pl = (const short8*)(wlo + ((rt * 16 + row) * KK + g * 8));
    const short8* pb = (const short8*)(wkb + ((ct * 16 + row) * KK + g * 8));

    f32x4 acc = {0.f, 0.f, 0.f, 0.f};
#pragma unroll
    for (int ks = 0; ks < 4; ++ks) {          // k advances 32 per step = 4 short8
        short8 ah = pa[ks * 4];
        short8 al = pl[ks * 4];
        short8 bv = pb[ks * 4];
        acc = __builtin_amdgcn_mfma_f32_16x16x32_bf16(ah, bv, acc, 0, 0, 0);
        acc = __builtin_amdgcn_mfma_f32_16x16x32_bf16(al, bv, acc, 0, 0, 0);
    }

    int colIdx = ct * 16 + row;               // D col = lane&15
    int rbase  = rt * 16 + g * 4;             // D row = g*4 + e
#pragma unroll
    for (int e = 0; e < 4; ++e) {
        int rr = rbase + e;
        int b  = rr / MM;
        int m  = rr - b * MM;
        int oidx = (colIdx < CC)
                 ? ((b * CC + colIdx) * MM + m)                 // re block
                 : (NOUT + (b * CC + (colIdx - CC)) * MM + m);  // im block
        out[oidx] = acc[e];
    }
}

// ---------------------------------------------------------------------------
// Legacy scalar kernel (round 4) retained for non-planar modes / tiny ws.
// ---------------------------------------------------------------------------
__global__ __launch_bounds__(256) void ISAC_conv_kernel(
    const float* __restrict__ x,
    const float* __restrict__ kr,
    const float* __restrict__ ki,
    float*       __restrict__ out,
    int mode)
{
    __shared__ unsigned int skc[CC * KPAD];

    for (int i = threadIdx.x; i < CC * KK; i += 256) {
        int c = i >> 7;
        int k = i & 127;
        unsigned int br = __float_as_uint(kr[i]);
        unsigned int bi = __float_as_uint(ki[i]);
        unsigned int hr = (br + 0x7FFFu + ((br >> 16) & 1u)) & 0xFFFF0000u;
        unsigned int hi = (bi + 0x7FFFu + ((bi >> 16) & 1u)) >> 16;
        skc[c * KPAD + k] = hr | hi;
    }
    __syncthreads();

    int id = blockIdx.x * 256 + threadIdx.x;
    int c  = id % CC;
    int t  = id / CC;
    int m  = t % MM;
    int b  = t / MM;

    const unsigned int* kc = skc + c * KPAD;
    const float*        xb = x + b * LL;
    const int base = m * KK;
    const float* p = xb + (m == 0 ? LL : base);

    unsigned int u0 = kc[0];
    float xv0  = xb[base];
    float accr = xv0 * __uint_as_float(u0 & 0xFFFF0000u);
    float acci = xv0 * __uint_as_float(u0 << 16);

#pragma unroll
    for (int j = 1; j < KK; ++j) {
        float        xv = p[-j];
        unsigned int u  = kc[j];
        accr = fmaf(xv, __uint_as_float(u & 0xFFFF0000u), accr);
        acci = fmaf(xv, __uint_as_float(u << 16),         acci);
    }

    int oidx = (b * CC + c) * MM + m;
    if (mode == 0) {
        out[oidx]        = accr;
        out[NOUT + oidx] = acci;
    } else if (mode == 1) {
        out[oidx] = accr;
    } else {
        reinterpret_cast<float2*>(out)[oidx] = make_float2(accr, acci);
    }
}

extern "C" void kernel_launch(void* const* d_in, const int* in_sizes, int n_in,
                              void* d_out, int out_size, void* d_ws, size_t ws_size,
                              hipStream_t stream) {
    const float* x  = (const float*)d_in[0];
    const float* kr = (const float*)d_in[1];
    const float* ki = (const float*)d_in[2];
    float* out = (float*)d_out;

    int mode;
    if (out_size == 2 * NOUT)      mode = 0;   // planar re|im (confirmed)
    else if (out_size == NOUT)     mode = 1;
    else                           mode = 2;

    const size_t ws_need = (size_t)(256000 + 256000 + 5120) * 4;  // 2.07 MB
    if (mode == 0 && d_ws != nullptr && ws_size >= ws_need) {
        unsigned int* whi = (unsigned int*)d_ws;
        unsigned int* wlo = whi + 256000;
        unsigned int* wkb = wlo + 256000;
        ISAC_prep<<<1020, 256, 0, stream>>>(x, kr, ki, whi, wlo, wkb);
        ISAC_gemm<<<(NTILE + 3) / 4, 256, 0, stream>>>(
            (const unsigned short*)whi, (const unsigned short*)wlo,
            (const unsigned short*)wkb, out);
    } else {
        const int grid = (NOUT + 255) / 256;
        ISAC_conv_kernel<<<grid, 256, 0, stream>>>(x, kr, ki, out, mode);
    }
}

// Round 3
// 61.354 us; speedup vs baseline: 1.0296x; 1.0296x over previous
//
#include <hip/hip_runtime.h>

// out[b,c,m] = sum_{j=0}^{127} x[b, (128m - j) mod 16000] * (kr[c,j] + i*ki[c,j])
//   x: (32, 1, 16000) fp32; kernels: (40, 128) fp32 each; out: (32, 40, 125) complex64
//
// Round 7: resubmit of round-6 fused MFMA GEMM (round 6 died to an infra
//   "container failed twice" before producing any measurement). Only change:
//   hardened the 4B-aligned float4 typedef to classic typedef syntax.
//
// Structure: stride==taps==128 -> disjoint tap windows -> GEMM
//   out[r=b*125+m][col] = sum_k A[r][k] * B[k][col],
//   A[r][k] = x[b, (128m-k) mod 16000]  (a reversed-window view of x),
//   B[k][col] = col<40 ? kr[col][k] : ki[col-40][k].
// 1250 independent 16x16 tiles, one per wave. Per wave: 24 vector loads,
//   ~150 VALU (in-register bf16 hi/lo split of x, RNE identical to legacy),
//   8 x mfma_f32_16x16x32_bf16 (hi+lo accumulated into same f32 acc).
// Fragment layouts (guide section 3, m89-verified):
//   A: row=lane&15, k=(lane>>4)*8+e ; B: col=lane&15, k=(lane>>4)*8+e
//   D: col=lane&15, row=(lane>>4)*4+e
#define BB     32
#define CC     40
#define LL     16000
#define KK     128
#define MM     125
#define NOUT   (BB * CC * MM)       // 160000 complex outputs
#define RTOT   (BB * MM)            // 4000 GEMM rows
#define NCOL   (2 * CC)             // 80 GEMM cols (re | im)
#define NTILE  ((RTOT / 16) * (NCOL / 16))   // 250 * 5 = 1250 tiles

typedef short  short8  __attribute__((ext_vector_type(8)));   // 8 bf16 (MFMA A/B)
typedef float  f32x4   __attribute__((ext_vector_type(4)));   // MFMA C/D frag
typedef unsigned int uint4v __attribute__((ext_vector_type(4)));

__device__ __forceinline__ unsigned int bf16h(float f) {     // RNE bf16 in low 16
    unsigned int u = __float_as_uint(f);
    return (u + 0x7FFFu + ((u >> 16) & 1u)) >> 16;
}

__global__ __launch_bounds__(256) void ISAC_fused(
    const float* __restrict__ x,     // B*L fp32
    const float* __restrict__ kr,    // C*K fp32
    const float* __restrict__ ki,    // C*K fp32
    float*       __restrict__ out,
    int mode)                        // 0=planar, 1=real-only, 2=interleaved
{
    int tile = blockIdx.x * 4 + (threadIdx.x >> 6);
    if (tile >= NTILE) return;
    int lane = threadIdx.x & 63;
    int rt   = tile / 5;             // row tile 0..249
    int ct   = tile - rt * 5;        // col tile 0..4
    int fr   = lane & 15;            // A-row / B-col / D-col index within tile
    int g    = lane >> 4;            // k-group (A/B), row-group (D)

    // A side: this lane's GEMM row
    int r = rt * 16 + fr;            // 0..3999
    int b = r / MM;
    int m = r - b * MM;
    const float* xb = x + b * LL;

    // B side: this lane's GEMM column
    int col = ct * 16 + fr;          // 0..79
    const float* kcol = (col < CC) ? (kr + col * KK) : (ki + (col - CC) * KK);

    f32x4 acc = {0.f, 0.f, 0.f, 0.f};

#pragma unroll
    for (int ks = 0; ks < 4; ++ks) {
        int kb = ks * 32 + g * 8;    // first tap of this lane's 8-elem run

        // Gather x: element v[i] holds tap k = kb + 7 - i (ascending address).
        float v[8];
        if (m != 0) {                // no wrap: 8 consecutive floats, reversed map
            const float* p = xb + (m * KK - kb - 7);
#pragma unroll
            for (int i = 0; i < 8; ++i) v[i] = p[i];
        } else {                     // m==0: taps wrap (k==0 -> 0, else LL-k)
#pragma unroll
            for (int i = 0; i < 8; ++i) {
                int k = kb + 7 - i;
                v[i] = xb[k == 0 ? 0 : (LL - k)];
            }
        }

        // hi = RNE bf16(x); lo = RNE bf16(x - float(hi)).  x_e = v[7-e].
        unsigned int h[8], q[8];
#pragma unroll
        for (int e = 0; e < 8; ++e) {
            float xe = v[7 - e];
            h[e] = bf16h(xe);
            float le = xe - __uint_as_float(h[e] << 16);
            q[e] = bf16h(le);
        }
        uint4v ahu = { h[0] | (h[1] << 16), h[2] | (h[3] << 16),
                       h[4] | (h[5] << 16), h[6] | (h[7] << 16) };
        uint4v alu = { q[0] | (q[1] << 16), q[2] | (q[3] << 16),
                       q[4] | (q[5] << 16), q[6] | (q[7] << 16) };

        // B: 8 consecutive taps from this lane's kernel row (L2-resident)
        const float* pB = kcol + kb;
        uint4v bvu = { bf16h(pB[0]) | (bf16h(pB[1]) << 16),
                       bf16h(pB[2]) | (bf16h(pB[3]) << 16),
                       bf16h(pB[4]) | (bf16h(pB[5]) << 16),
                       bf16h(pB[6]) | (bf16h(pB[7]) << 16) };

        short8 ah = __builtin_bit_cast(short8, ahu);
        short8 al = __builtin_bit_cast(short8, alu);
        short8 bv = __builtin_bit_cast(short8, bvu);
        acc = __builtin_amdgcn_mfma_f32_16x16x32_bf16(ah, bv, acc, 0, 0, 0);
        acc = __builtin_amdgcn_mfma_f32_16x16x32_bf16(al, bv, acc, 0, 0, 0);
    }

    // Epilogue: D col = lane&15 (== our GEMM col), D row = g*4 + e.
    int c  = (col < CC) ? col : (col - CC);
#pragma unroll
    for (int e = 0; e < 4; ++e) {
        int rr = rt * 16 + g * 4 + e;
        int ob = rr / MM;
        int om = rr - ob * MM;
        int oidx = (ob * CC + c) * MM + om;    // flat complex index (b,c,m)
        float val = acc[e];
        if (mode == 0) {
            out[(col < CC ? 0 : NOUT) + oidx] = val;
        } else if (mode == 2) {
            out[2 * oidx + (col < CC ? 0 : 1)] = val;
        } else if (col < CC) {                 // mode 1: real only
            out[oidx] = val;
        }
    }
}

extern "C" void kernel_launch(void* const* d_in, const int* in_sizes, int n_in,
                              void* d_out, int out_size, void* d_ws, size_t ws_size,
                              hipStream_t stream) {
    const float* x  = (const float*)d_in[0];
    const float* kr = (const float*)d_in[1];
    const float* ki = (const float*)d_in[2];
    float* out = (float*)d_out;

    // Mode detection (out_size units unknown: elements => planar; bytes =>
    // interleaved). The SAME fused kernel runs either way -- the gate only
    // selects the epilogue store pattern.
    int mode;
    if (out_size == 2 * NOUT)      mode = 0;   // planar re|im
    else if (out_size == NOUT)     mode = 1;   // real only
    else                           mode = 2;   // interleaved complex64

    const int grid = (NTILE + 3) / 4;          // 313 blocks x 4 waves
    ISAC_fused<<<grid, 256, 0, stream>>>(x, kr, ki, out, mode);
}